// Round 8
// baseline (3260.035 us; speedup 1.0000x reference)
//
#include <hip/hip_runtime.h>
#include <hip/hip_bf16.h>

typedef __bf16 bf16x8 __attribute__((ext_vector_type(8)));
typedef float f32x4 __attribute__((ext_vector_type(4)));

__device__ __forceinline__ unsigned short f2bf(float f) {
    unsigned int u = __builtin_bit_cast(unsigned int, f);
    u += 0x7FFFu + ((u >> 16) & 1u);
    return (unsigned short)(u >> 16);
}
__device__ __forceinline__ float bf2f(unsigned short s) {
    unsigned int u = ((unsigned int)s) << 16;
    return __builtin_bit_cast(float, u);
}

// Coherent (L1/L2-bypass, L3-served) 16B load: issue only; caller batches a
// single s_waitcnt vmcnt(0) + sched_barrier afterwards (guide §5.5 rule 18).
__device__ __forceinline__ void ldg_c(uint4& d, const void* p) {
    asm volatile("global_load_dwordx4 %0, %1, off sc0 sc1" : "=v"(d) : "v"(p));
}
__device__ __forceinline__ void vm_drain() {
    asm volatile("s_waitcnt vmcnt(0)" ::: "memory");
    __builtin_amdgcn_sched_barrier(0);
}
// Coherent write-through 16-bit store.
__device__ __forceinline__ void stg_c16(void* p, unsigned short v) {
    asm volatile("global_store_short %0, %1, off sc0 sc1" :: "v"(p), "v"(v) : "memory");
}

// Wave-parallel flag wait: 64 lanes each watch one CU's flag word.
__device__ __forceinline__ void wait_flags(const unsigned* f, unsigned tgt) {
    int lane = threadIdx.x & 63;
    for (;;) {
        unsigned v = __hip_atomic_load(f + lane, __ATOMIC_RELAXED, __HIP_MEMORY_SCOPE_AGENT);
        if (__all((int)(v >= tgt))) break;
        __builtin_amdgcn_s_sleep(1);
    }
}

// ---------------- prep: x -> split bf16 hi/lo in MFMA B-fragment layout ----------------
// layout: [t(200)][nt(8)][kc(16)][lane(64)][e(8)]; batch = nt*16+(lane&15), k = kc*32+(lane>>4)*8+e
__global__ void prep_x(const float* __restrict__ x,
                       unsigned short* __restrict__ xh,
                       unsigned short* __restrict__ xl) {
    int g = blockIdx.x * 256 + threadIdx.x;   // 1,638,400 frags
    if (g >= 1638400) return;
    int lane = g & 63;
    int kc   = (g >> 6) & 15;
    int nt   = (g >> 10) & 7;
    int t    = g >> 13;
    int batch = nt * 16 + (lane & 15);
    int k = kc * 32 + (lane >> 4) * 8;
    const float* s = x + ((size_t)batch * 200 + t) * 512 + k;
    float4 v0 = *(const float4*)s;
    float4 v1 = *(const float4*)(s + 4);
    float vv[8] = {v0.x, v0.y, v0.z, v0.w, v1.x, v1.y, v1.z, v1.w};
    unsigned int ph[4], pl[4];
    #pragma unroll
    for (int j = 0; j < 4; ++j) {
        float a = vv[2*j], b = vv[2*j+1];
        unsigned short ha = f2bf(a), hb = f2bf(b);
        unsigned short la = f2bf(a - bf2f(ha)), lb = f2bf(b - bf2f(hb));
        ph[j] = (unsigned)ha | ((unsigned)hb << 16);
        pl[j] = (unsigned)la | ((unsigned)lb << 16);
    }
    ((uint4*)xh)[g] = make_uint4(ph[0], ph[1], ph[2], ph[3]);
    ((uint4*)xl)[g] = make_uint4(pl[0], pl[1], pl[2], pl[3]);
}

// ---------------- prep: weights -> per-CU LDS image blocks ----------------
// dst block per (wu = dir*2+layer, cu 0..63): 8192 frags of 16B (131072 B):
//   frag idx within block = mat*2048 + mt*1024 + kc*64 + lane
//   mat: 0=ihH 1=ihL 2=hhH 3=hhL; within frag: row r=lane&15, k=kc*32+(lane>>4)*8+e
//   global gate row = (2*mt + (r>>3))*512 + cu*8 + (r&7)
__global__ void prep_w(const float* __restrict__ W,     // [2][2048][512] f32
                       unsigned short* __restrict__ wprep,
                       int dir, int isHH) {
    int g = blockIdx.x * 256 + threadIdx.x;   // 262,144
    if (g >= 262144) return;
    int lane = g & 63;
    int kc   = (g >> 6) & 15;
    int mt   = (g >> 10) & 1;
    int cu   = (g >> 11) & 63;
    int l    = g >> 17;
    int r = lane & 15;
    int grow = (2 * mt + (r >> 3)) * 512 + cu * 8 + (r & 7);
    int k = kc * 32 + (lane >> 4) * 8;
    const float* s = W + ((size_t)l * 2048 + grow) * 512 + k;
    float4 v0 = *(const float4*)s;
    float4 v1 = *(const float4*)(s + 4);
    float vv[8] = {v0.x, v0.y, v0.z, v0.w, v1.x, v1.y, v1.z, v1.w};
    unsigned int ph[4], pl[4];
    #pragma unroll
    for (int j = 0; j < 4; ++j) {
        float a = vv[2*j], b = vv[2*j+1];
        unsigned short ha = f2bf(a), hb = f2bf(b);
        unsigned short la = f2bf(a - bf2f(ha)), lb = f2bf(b - bf2f(hb));
        ph[j] = (unsigned)ha | ((unsigned)hb << 16);
        pl[j] = (unsigned)la | ((unsigned)lb << 16);
    }
    size_t blk = ((size_t)(dir * 2 + l) * 64 + cu) * 8192;
    size_t fH = blk + (size_t)((isHH * 2 + 0) * 2048 + mt * 1024 + kc * 64 + lane);
    size_t fL = blk + (size_t)((isHH * 2 + 1) * 2048 + mt * 1024 + kc * 64 + lane);
    ((uint4*)wprep)[fH] = make_uint4(ph[0], ph[1], ph[2], ph[3]);
    ((uint4*)wprep)[fL] = make_uint4(pl[0], pl[1], pl[2], pl[3]);
}

__global__ void bsum_k(const float* __restrict__ bih_f, const float* __restrict__ bhh_f,
                       const float* __restrict__ bih_b, const float* __restrict__ bhh_b,
                       float* __restrict__ bsum) {
    int i = blockIdx.x * 256 + threadIdx.x;   // 8192 = [dir][l][2048]
    if (i < 8192) {
        int dir = i >> 12, rem = i & 4095;
        const float* bi = dir ? bih_b : bih_f;
        const float* bh = dir ? bhh_b : bhh_f;
        bsum[i] = bi[rem] + bh[rem];
    }
}

__global__ void reset_k(uint4* __restrict__ p) {  // zero h_hi | h_lo | flags (3,146,752 B)
    int g = blockIdx.x * 256 + threadIdx.x;
    if (g < 196672) p[g] = make_uint4(0, 0, 0, 0);
}

// ---------------- persistent LSTM (cooperative launch, flag-vector barriers) --------
// 256 WGs (1/CU) x 512 threads. unit = xcd>>1 (slot=unit>>1, dir=unit&1);
// CU owns 8 hidden units (hj0 = cu8*8): gate rows {q*512+hj0..+7}, all 128 batches.
// Waves: kh = wave&3 (K-split, kc = kh*4+kcl), nh = wave>>2 (batch half).
// Weights LDS-resident all 200 steps; c-state in LDS; h triple-buffered in global
// (parity = t mod 3), accessed ONLY via sc0/sc1-coherent loads/stores. Barrier =
// per-CU flag words (no RMW contention): producer stores flag=tau+1; consumers
// poll 64 flags with one 64-lane load (wave0: own unit, wave1: sibling unit).
__global__ void __launch_bounds__(512)
lstm_persist(const unsigned short* __restrict__ xh,
             const unsigned short* __restrict__ xl,
             const unsigned short* __restrict__ wprep,
             const float*          __restrict__ bsum,
             unsigned short*       __restrict__ h_hi,   // [(slot*3+parity)*2+dir] x 65536
             unsigned short*       __restrict__ h_lo,
             const int*            __restrict__ lens,
             float*                __restrict__ dout,   // [128][200][1024]
             unsigned*             __restrict__ flagv)  // [unit4][cu64]
{
    extern __shared__ char smem[];
    float* exch = (float*)(smem + 131072);            // [kh4][row32][33] = 16,896 B
    float* cst  = (float*)(smem + 131072 + 16896);    // [u8][132] = 4,224 B

    const int bid  = blockIdx.x;
    const int xcd  = bid & 7;
    const int unit = xcd >> 1;                        // slot-major: slot*2 + dir
    const int slot = unit >> 1, dir = unit & 1;
    const int cu8  = ((xcd & 1) << 5) | (bid >> 3);   // 0..63
    const int hj0  = cu8 * 8;
    const int tid  = threadIdx.x;
    const int lane = tid & 63, wv = tid >> 6;
    const int kh = wv & 3, nh = wv >> 2;
    const int l15 = lane & 15;
    const int wsel = dir * 2 + slot;                  // dir-major, matches prep_w/bsum

    const int sib = slot ? dir : (2 + dir);           // other slot, same dir
    unsigned* own_f = flagv + unit * 64;
    unsigned* sib_f = flagv + sib * 64;

    // ---- stage weights into LDS (one-time) ----
    {
        const uint4* src = (const uint4*)wprep + ((size_t)(wsel * 64 + cu8) * 8192);
        uint4* dst = (uint4*)smem;
        #pragma unroll
        for (int i = 0; i < 16; ++i) dst[tid + i * 512] = src[tid + i * 512];
    }
    for (int i = tid; i < 8 * 132; i += 512) cst[i] = 0.f;
    __syncthreads();

    // ---- loop invariants ----
    int lenv[4];
    #pragma unroll
    for (int nt = 0; nt < 4; ++nt) lenv[nt] = lens[(nh * 4 + nt) * 16 + l15];

    const int cu_u = tid >> 5, cu_b = tid & 31;       // cell role (tid < 256)
    float bias_c[4];
    int   len_c[4];
    if (tid < 256) {
        #pragma unroll
        for (int q = 0; q < 4; ++q) bias_c[q] = bsum[wsel * 2048 + q * 512 + hj0 + cu_u];
        #pragma unroll
        for (int c = 0; c < 4; ++c) {
            int gb = (cu_b < 16) ? (c * 16 + cu_b) : (64 + c * 16 + (cu_b - 16));
            len_c[c] = lens[gb];
        }
    }

    const size_t lofs = (size_t)lane * 8;

    for (int tau = 0; tau <= 200; ++tau) {
        const int t = slot ? (tau - 1) : tau;
        const bool active = (t >= 0 && t <= 199);
        int t_eff = 0, p_w = 0, p_r = 0;
        if (active) { t_eff = dir ? (199 - t) : t; p_w = t % 3; p_r = (t + 2) % 3; }

        f32x4 acc[2][4];
        #pragma unroll
        for (int mt = 0; mt < 2; ++mt)
            #pragma unroll
            for (int nt = 0; nt < 4; ++nt)
                acc[mt][nt] = (f32x4){0.f, 0.f, 0.f, 0.f};

        // ---- Phase 1 (slot0 only): ih * x_t — independent of the recurrence ----
        if (slot == 0 && active) {
            const unsigned short* XH = xh + (size_t)t_eff * 65536;
            const unsigned short* XL = xl + (size_t)t_eff * 65536;
            #pragma unroll
            for (int kcl = 0; kcl < 4; ++kcl) {
                int kc = kh * 4 + kcl;
                bf16x8 bxh[4], bxl[4];
                #pragma unroll
                for (int nt = 0; nt < 4; ++nt) {
                    size_t bo = (size_t)(nh * 4 + nt) * 8192 + (size_t)kc * 512 + lofs;
                    bxh[nt] = *(const bf16x8*)(XH + bo);
                    bxl[nt] = *(const bf16x8*)(XL + bo);
                }
                #pragma unroll
                for (int mt = 0; mt < 2; ++mt) {
                    const char* ab = smem + mt * 16384 + kc * 1024 + lane * 16;
                    bf16x8 aih = *(const bf16x8*)(ab);
                    bf16x8 ail = *(const bf16x8*)(ab + 32768);
                    #pragma unroll
                    for (int nt = 0; nt < 4; ++nt) {
                        f32x4 a = acc[mt][nt];
                        a = __builtin_amdgcn_mfma_f32_16x16x32_bf16(aih, bxh[nt], a, 0, 0, 0);
                        a = __builtin_amdgcn_mfma_f32_16x16x32_bf16(aih, bxl[nt], a, 0, 0, 0);
                        a = __builtin_amdgcn_mfma_f32_16x16x32_bf16(ail, bxh[nt], a, 0, 0, 0);
                        acc[mt][nt] = a;
                    }
                }
            }
        }

        // ---- wait for dependencies (parallel wave polls, no RMW contention) ----
        {
            unsigned tgt = (unsigned)tau;
            if (wv == 0) wait_flags(own_f, tgt);                       // own unit done tau-1
            if (slot == 1) { if (wv == 1) wait_flags(sib_f, tgt); }    // data dep
            else if (tau >= 2) { if (wv == 1) wait_flags(sib_f, tgt - 1); }  // WAR slack
        }
        __syncthreads();

        if (active) {
            const unsigned short* HH = h_hi + ((size_t)((slot * 3 + p_r) * 2 + dir) << 16);
            const unsigned short* HL = h_lo + ((size_t)((slot * 3 + p_r) * 2 + dir) << 16);

            // ---- Phase 2: recurrent terms (and, for slot1, the layer0-h input) ----
            if (slot == 0) {
                uint4 vhh[4][4], vhl[4][4];
                #pragma unroll
                for (int kcl = 0; kcl < 4; ++kcl)
                    #pragma unroll
                    for (int nt = 0; nt < 4; ++nt) {
                        size_t bo = (size_t)(nh * 4 + nt) * 8192
                                  + (size_t)(kh * 4 + kcl) * 512 + lofs;
                        ldg_c(vhh[kcl][nt], HH + bo);
                        ldg_c(vhl[kcl][nt], HL + bo);
                    }
                vm_drain();
                #pragma unroll
                for (int kcl = 0; kcl < 4; ++kcl) {
                    int kc = kh * 4 + kcl;
                    #pragma unroll
                    for (int mt = 0; mt < 2; ++mt) {
                        const char* ab = smem + mt * 16384 + kc * 1024 + lane * 16;
                        bf16x8 ahh = *(const bf16x8*)(ab + 65536);
                        bf16x8 ahl = *(const bf16x8*)(ab + 98304);
                        #pragma unroll
                        for (int nt = 0; nt < 4; ++nt) {
                            bf16x8 bh = __builtin_bit_cast(bf16x8, vhh[kcl][nt]);
                            bf16x8 bl = __builtin_bit_cast(bf16x8, vhl[kcl][nt]);
                            f32x4 a = acc[mt][nt];
                            a = __builtin_amdgcn_mfma_f32_16x16x32_bf16(ahh, bh, a, 0, 0, 0);
                            a = __builtin_amdgcn_mfma_f32_16x16x32_bf16(ahh, bl, a, 0, 0, 0);
                            a = __builtin_amdgcn_mfma_f32_16x16x32_bf16(ahl, bh, a, 0, 0, 0);
                            acc[mt][nt] = a;
                        }
                    }
                }
            } else {
                int p_x = t % 3;                      // layer0 wrote h_t at parity t%3
                const unsigned short* XHc = h_hi + ((size_t)(p_x * 2 + dir) << 16);
                const unsigned short* XLc = h_lo + ((size_t)(p_x * 2 + dir) << 16);
                uint4 va[4][4], vb[4][4];
                // pass A: layer0-h (the x input), masked
                #pragma unroll
                for (int kcl = 0; kcl < 4; ++kcl)
                    #pragma unroll
                    for (int nt = 0; nt < 4; ++nt) {
                        size_t bo = (size_t)(nh * 4 + nt) * 8192
                                  + (size_t)(kh * 4 + kcl) * 512 + lofs;
                        ldg_c(va[kcl][nt], XHc + bo);
                        ldg_c(vb[kcl][nt], XLc + bo);
                    }
                vm_drain();
                #pragma unroll
                for (int kcl = 0; kcl < 4; ++kcl) {
                    int kc = kh * 4 + kcl;
                    #pragma unroll
                    for (int nt = 0; nt < 4; ++nt)
                        if (!(t_eff < lenv[nt])) {
                            va[kcl][nt] = make_uint4(0, 0, 0, 0);
                            vb[kcl][nt] = make_uint4(0, 0, 0, 0);
                        }
                    #pragma unroll
                    for (int mt = 0; mt < 2; ++mt) {
                        const char* ab = smem + mt * 16384 + kc * 1024 + lane * 16;
                        bf16x8 aih = *(const bf16x8*)(ab);
                        bf16x8 ail = *(const bf16x8*)(ab + 32768);
                        #pragma unroll
                        for (int nt = 0; nt < 4; ++nt) {
                            bf16x8 xhv = __builtin_bit_cast(bf16x8, va[kcl][nt]);
                            bf16x8 xlv = __builtin_bit_cast(bf16x8, vb[kcl][nt]);
                            f32x4 a = acc[mt][nt];
                            a = __builtin_amdgcn_mfma_f32_16x16x32_bf16(aih, xhv, a, 0, 0, 0);
                            a = __builtin_amdgcn_mfma_f32_16x16x32_bf16(aih, xlv, a, 0, 0, 0);
                            a = __builtin_amdgcn_mfma_f32_16x16x32_bf16(ail, xhv, a, 0, 0, 0);
                            acc[mt][nt] = a;
                        }
                    }
                }
                // pass B: own h_{t-1} (reuse registers)
                #pragma unroll
                for (int kcl = 0; kcl < 4; ++kcl)
                    #pragma unroll
                    for (int nt = 0; nt < 4; ++nt) {
                        size_t bo = (size_t)(nh * 4 + nt) * 8192
                                  + (size_t)(kh * 4 + kcl) * 512 + lofs;
                        ldg_c(va[kcl][nt], HH + bo);
                        ldg_c(vb[kcl][nt], HL + bo);
                    }
                vm_drain();
                #pragma unroll
                for (int kcl = 0; kcl < 4; ++kcl) {
                    int kc = kh * 4 + kcl;
                    #pragma unroll
                    for (int mt = 0; mt < 2; ++mt) {
                        const char* ab = smem + mt * 16384 + kc * 1024 + lane * 16;
                        bf16x8 ahh = *(const bf16x8*)(ab + 65536);
                        bf16x8 ahl = *(const bf16x8*)(ab + 98304);
                        #pragma unroll
                        for (int nt = 0; nt < 4; ++nt) {
                            bf16x8 bh = __builtin_bit_cast(bf16x8, va[kcl][nt]);
                            bf16x8 bl = __builtin_bit_cast(bf16x8, vb[kcl][nt]);
                            f32x4 a = acc[mt][nt];
                            a = __builtin_amdgcn_mfma_f32_16x16x32_bf16(ahh, bh, a, 0, 0, 0);
                            a = __builtin_amdgcn_mfma_f32_16x16x32_bf16(ahh, bl, a, 0, 0, 0);
                            a = __builtin_amdgcn_mfma_f32_16x16x32_bf16(ahl, bh, a, 0, 0, 0);
                            acc[mt][nt] = a;
                        }
                    }
                }
            }

            unsigned short* HwH = h_hi + ((size_t)((slot * 3 + p_w) * 2 + dir) << 16);
            unsigned short* HwL = h_lo + ((size_t)((slot * 3 + p_w) * 2 + dir) << 16);

            const int crow = (lane >> 4) * 4;
            #pragma unroll
            for (int c = 0; c < 4; ++c) {
                #pragma unroll
                for (int mt = 0; mt < 2; ++mt)
                    #pragma unroll
                    for (int r = 0; r < 4; ++r) {
                        int rr = mt * 16 + crow + r;
                        exch[(kh * 32 + rr) * 33 + nh * 16 + l15] = acc[mt][c][r];
                    }
                __syncthreads();
                if (tid < 256) {
                    float g[4];
                    #pragma unroll
                    for (int q = 0; q < 4; ++q) {
                        int row = q * 8 + cu_u;
                        g[q] = exch[(0 + row) * 33 + cu_b] + exch[(32 + row) * 33 + cu_b]
                             + exch[(64 + row) * 33 + cu_b] + exch[(96 + row) * 33 + cu_b]
                             + bias_c[q];
                    }
                    int gb = (cu_b < 16) ? (c * 16 + cu_b) : (64 + c * 16 + (cu_b - 16));
                    float cv = cst[cu_u * 132 + gb];
                    float iG = 1.f / (1.f + expf(-g[0]));
                    float fG = 1.f / (1.f + expf(-g[1]));
                    float gG = tanhf(g[2]);
                    float oG = 1.f / (1.f + expf(-g[3]));
                    float cn = fG * cv + iG * gG;
                    cst[cu_u * 132 + gb] = cn;
                    float hn = oG * tanhf(cn);
                    unsigned short hh_ = f2bf(hn);
                    unsigned short hl_ = f2bf(hn - bf2f(hh_));
                    int hj = hj0 + cu_u;
                    size_t ho = (((size_t)(gb >> 4) * 16 + (hj >> 5)) * 64
                                 + ((hj >> 3) & 3) * 16 + (gb & 15)) * 8 + (hj & 7);
                    stg_c16(HwH + ho, hh_);
                    stg_c16(HwL + ho, hl_);
                    if (slot) {
                        float hm = (t_eff < len_c[c]) ? hn : 0.f;
                        dout[((size_t)gb * 200 + t_eff) * 1024 + dir * 512 + hj] = hm;
                    }
                }
                __syncthreads();
            }
            // drain the coherent h stores (asm stores are invisible to the
            // compiler's barrier waitcnt) before signaling completion
            if (tid < 256) asm volatile("s_waitcnt vmcnt(0)" ::: "memory");
            __syncthreads();
        }

        // ---- signal completion of iteration tau (plain coherent store, no RMW) ----
        if (tid == 0)
            __hip_atomic_store(own_f + cu8, (unsigned)(tau + 1),
                               __ATOMIC_RELAXED, __HIP_MEMORY_SCOPE_AGENT);
    }
}

// ---------------- host ----------------
extern "C" void kernel_launch(void* const* d_in, const int* in_sizes, int n_in,
                              void* d_out, int out_size, void* d_ws, size_t ws_size,
                              hipStream_t stream) {
    const float* x     = (const float*)d_in[0];
    const int*   lens  = (const int*)d_in[1];     // int32 (JAX x64-disabled)
    const float* Wih_f = (const float*)d_in[2];
    const float* Whh_f = (const float*)d_in[3];
    const float* bih_f = (const float*)d_in[4];
    const float* bhh_f = (const float*)d_in[5];
    const float* Wih_b = (const float*)d_in[6];
    const float* Whh_b = (const float*)d_in[7];
    const float* bih_b = (const float*)d_in[8];
    const float* bhh_b = (const float*)d_in[9];
    float* out = (float*)d_out;
    char* ws = (char*)d_ws;
    if (ws_size < 89162752) return;

    unsigned short* xh    = (unsigned short*)(ws);                 // 26,214,400
    unsigned short* xl    = (unsigned short*)(ws + 26214400);      // 26,214,400
    unsigned short* wprep = (unsigned short*)(ws + 52428800);      // 33,554,432
    float*          bsum  = (float*)(ws + 85983232);               //     32,768
    unsigned short* hhi   = (unsigned short*)(ws + 86016000);      //  1,572,864
    unsigned short* hlo   = (unsigned short*)(ws + 87588864);      //  1,572,864
    unsigned*       flg   = (unsigned*)(ws + 89161728);            //      1,024

    prep_x<<<6400, 256, 0, stream>>>(x, xh, xl);
    prep_w<<<1024, 256, 0, stream>>>(Wih_f, wprep, 0, 0);
    prep_w<<<1024, 256, 0, stream>>>(Whh_f, wprep, 0, 1);
    prep_w<<<1024, 256, 0, stream>>>(Wih_b, wprep, 1, 0);
    prep_w<<<1024, 256, 0, stream>>>(Whh_b, wprep, 1, 1);
    bsum_k<<<32, 256, 0, stream>>>(bih_f, bhh_f, bih_b, bhh_b, bsum);
    reset_k<<<769, 256, 0, stream>>>((uint4*)hhi);   // zeroes hhi | hlo | flags (contiguous)

    static const int LDS_BYTES = 131072 + 16896 + 4224;  // 152,192
    hipFuncSetAttribute(reinterpret_cast<const void*>(lstm_persist),
                        hipFuncAttributeMaxDynamicSharedMemorySize, LDS_BYTES);

    void* args[] = {(void*)&xh, (void*)&xl, (void*)&wprep, (void*)&bsum,
                    (void*)&hhi, (void*)&hlo, (void*)&lens, (void*)&out, (void*)&flg};
    hipLaunchCooperativeKernel(reinterpret_cast<void*>(lstm_persist),
                               dim3(256), dim3(512), args, LDS_BYTES, stream);
}

// Round 9
// 2461.813 us; speedup vs baseline: 1.3242x; 1.3242x over previous
//
#include <hip/hip_runtime.h>
#include <hip/hip_bf16.h>

typedef __bf16 bf16x8 __attribute__((ext_vector_type(8)));
typedef _Float16 f16x8 __attribute__((ext_vector_type(8)));
typedef float f32x4 __attribute__((ext_vector_type(4)));

__device__ __forceinline__ unsigned short f2bf(float f) {
    unsigned int u = __builtin_bit_cast(unsigned int, f);
    u += 0x7FFFu + ((u >> 16) & 1u);
    return (unsigned short)(u >> 16);
}
__device__ __forceinline__ float bf2f(unsigned short s) {
    unsigned int u = ((unsigned int)s) << 16;
    return __builtin_bit_cast(float, u);
}

// Coherent (L1/L2-bypass, L3-served) 16B load: issue only; caller batches a
// single s_waitcnt vmcnt(0) + sched_barrier afterwards (guide §5.5 rule 18).
__device__ __forceinline__ void ldg_c(uint4& d, const void* p) {
    asm volatile("global_load_dwordx4 %0, %1, off sc0 sc1" : "=v"(d) : "v"(p));
}
__device__ __forceinline__ void vm_drain() {
    asm volatile("s_waitcnt vmcnt(0)" ::: "memory");
    __builtin_amdgcn_sched_barrier(0);
}
// Coherent write-through 16-bit store.
__device__ __forceinline__ void stg_c16(void* p, unsigned short v) {
    asm volatile("global_store_short %0, %1, off sc0 sc1" :: "v"(p), "v"(v) : "memory");
}

// Wave-parallel flag wait: 64 lanes each watch one CU's flag word.
__device__ __forceinline__ void wait_flags(const unsigned* f, unsigned tgt) {
    int lane = threadIdx.x & 63;
    for (;;) {
        unsigned v = __hip_atomic_load(f + lane, __ATOMIC_RELAXED, __HIP_MEMORY_SCOPE_AGENT);
        if (__all((int)(v >= tgt))) break;
        __builtin_amdgcn_s_sleep(1);
    }
}

// ---------------- prep: x -> split bf16 hi/lo in MFMA B-fragment layout ----------------
// layout: [t(200)][nt(8)][kc(16)][lane(64)][e(8)]; batch = nt*16+(lane&15), k = kc*32+(lane>>4)*8+e
__global__ void prep_x(const float* __restrict__ x,
                       unsigned short* __restrict__ xh,
                       unsigned short* __restrict__ xl) {
    int g = blockIdx.x * 256 + threadIdx.x;   // 1,638,400 frags
    if (g >= 1638400) return;
    int lane = g & 63;
    int kc   = (g >> 6) & 15;
    int nt   = (g >> 10) & 7;
    int t    = g >> 13;
    int batch = nt * 16 + (lane & 15);
    int k = kc * 32 + (lane >> 4) * 8;
    const float* s = x + ((size_t)batch * 200 + t) * 512 + k;
    float4 v0 = *(const float4*)s;
    float4 v1 = *(const float4*)(s + 4);
    float vv[8] = {v0.x, v0.y, v0.z, v0.w, v1.x, v1.y, v1.z, v1.w};
    unsigned int ph[4], pl[4];
    #pragma unroll
    for (int j = 0; j < 4; ++j) {
        float a = vv[2*j], b = vv[2*j+1];
        unsigned short ha = f2bf(a), hb = f2bf(b);
        unsigned short la = f2bf(a - bf2f(ha)), lb = f2bf(b - bf2f(hb));
        ph[j] = (unsigned)ha | ((unsigned)hb << 16);
        pl[j] = (unsigned)la | ((unsigned)lb << 16);
    }
    ((uint4*)xh)[g] = make_uint4(ph[0], ph[1], ph[2], ph[3]);
    ((uint4*)xl)[g] = make_uint4(pl[0], pl[1], pl[2], pl[3]);
}

// ---------------- prep: weights -> per-CU LDS image blocks ----------------
// dst block per (wu = dir*2+layer, cu 0..63): 8192 frags of 16B (131072 B):
//   frag idx within block = mat*2048 + mt*1024 + kc*64 + lane
//   mat: 0=ihH 1=ihL 2=hhH 3=hhL
// Format: layer0 ih = split-bf16 (multiplies x); layer1 ih and all hh =
// split-fp16 (multiply fp16 h streams).
__global__ void prep_w(const float* __restrict__ W,     // [2][2048][512] f32
                       unsigned short* __restrict__ wprep,
                       int dir, int isHH) {
    int g = blockIdx.x * 256 + threadIdx.x;   // 262,144
    if (g >= 262144) return;
    int lane = g & 63;
    int kc   = (g >> 6) & 15;
    int mt   = (g >> 10) & 1;
    int cu   = (g >> 11) & 63;
    int l    = g >> 17;
    int r = lane & 15;
    int grow = (2 * mt + (r >> 3)) * 512 + cu * 8 + (r & 7);
    int k = kc * 32 + (lane >> 4) * 8;
    const float* s = W + ((size_t)l * 2048 + grow) * 512 + k;
    float4 v0 = *(const float4*)s;
    float4 v1 = *(const float4*)(s + 4);
    float vv[8] = {v0.x, v0.y, v0.z, v0.w, v1.x, v1.y, v1.z, v1.w};
    bool f16fmt = isHH || (l == 1);
    unsigned int ph[4], pl[4];
    #pragma unroll
    for (int j = 0; j < 4; ++j) {
        float a = vv[2*j], b = vv[2*j+1];
        unsigned short ha, hb, la, lb;
        if (f16fmt) {
            _Float16 fa = (_Float16)a, fb = (_Float16)b;
            _Float16 ra = (_Float16)(a - (float)fa), rb = (_Float16)(b - (float)fb);
            ha = __builtin_bit_cast(unsigned short, fa);
            hb = __builtin_bit_cast(unsigned short, fb);
            la = __builtin_bit_cast(unsigned short, ra);
            lb = __builtin_bit_cast(unsigned short, rb);
        } else {
            ha = f2bf(a); hb = f2bf(b);
            la = f2bf(a - bf2f(ha)); lb = f2bf(b - bf2f(hb));
        }
        ph[j] = (unsigned)ha | ((unsigned)hb << 16);
        pl[j] = (unsigned)la | ((unsigned)lb << 16);
    }
    size_t blk = ((size_t)(dir * 2 + l) * 64 + cu) * 8192;
    size_t fH = blk + (size_t)((isHH * 2 + 0) * 2048 + mt * 1024 + kc * 64 + lane);
    size_t fL = blk + (size_t)((isHH * 2 + 1) * 2048 + mt * 1024 + kc * 64 + lane);
    ((uint4*)wprep)[fH] = make_uint4(ph[0], ph[1], ph[2], ph[3]);
    ((uint4*)wprep)[fL] = make_uint4(pl[0], pl[1], pl[2], pl[3]);
}

__global__ void bsum_k(const float* __restrict__ bih_f, const float* __restrict__ bhh_f,
                       const float* __restrict__ bih_b, const float* __restrict__ bhh_b,
                       float* __restrict__ bsum) {
    int i = blockIdx.x * 256 + threadIdx.x;   // 8192 = [dir][l][2048]
    if (i < 8192) {
        int dir = i >> 12, rem = i & 4095;
        const float* bi = dir ? bih_b : bih_f;
        const float* bh = dir ? bhh_b : bhh_f;
        bsum[i] = bi[rem] + bh[rem];
    }
}

__global__ void reset_k(uint4* __restrict__ p) {  // zero hbuf | flags (2,098,176 B)
    int g = blockIdx.x * 256 + threadIdx.x;
    if (g < 131136) p[g] = make_uint4(0, 0, 0, 0);
}

// ---------------- persistent LSTM (cooperative launch, flag-vector barriers) --------
// 256 WGs (1/CU) x 512 threads. unit = xcd>>1 (slot=unit>>1, dir=unit&1);
// CU owns 8 hidden units (hj0 = cu8*8): gate rows {q*512+hj0..+7}, all 128 batches.
// Waves: kh = wave&3 (K-split), nh = wave>>2 (batch half).
// Weights LDS-resident (layer0-ih split-bf16; layer1-ih + hh split-fp16);
// c-state in LDS; h = single fp16 stream, QUAD-buffered (parity = t mod 4) in
// global, accessed only via sc0/sc1-coherent loads/stores. Flag barrier as r8.
__global__ void __launch_bounds__(512)
lstm_persist(const unsigned short* __restrict__ xh,
             const unsigned short* __restrict__ xl,
             const unsigned short* __restrict__ wprep,
             const float*          __restrict__ bsum,
             unsigned short*       __restrict__ hbuf,   // [(slot*4+parity)*2+dir] x 65536 fp16
             const int*            __restrict__ lens,
             float*                __restrict__ dout,   // [128][200][1024]
             unsigned*             __restrict__ flagv)  // [unit4][cu64]
{
    extern __shared__ char smem[];
    float* exch = (float*)(smem + 131072);            // [kh4][row32][33] = 16,896 B
    float* cst  = (float*)(smem + 131072 + 16896);    // [u8][132] = 4,224 B

    const int bid  = blockIdx.x;
    const int xcd  = bid & 7;
    const int unit = xcd >> 1;                        // slot-major: slot*2 + dir
    const int slot = unit >> 1, dir = unit & 1;
    const int cu8  = ((xcd & 1) << 5) | (bid >> 3);   // 0..63
    const int hj0  = cu8 * 8;
    const int tid  = threadIdx.x;
    const int lane = tid & 63, wv = tid >> 6;
    const int kh = wv & 3, nh = wv >> 2;
    const int l15 = lane & 15;
    const int wsel = dir * 2 + slot;                  // dir-major, matches prep_w/bsum

    const int sib = slot ? dir : (2 + dir);           // other slot, same dir
    unsigned* own_f = flagv + unit * 64;
    unsigned* sib_f = flagv + sib * 64;

    // ---- stage weights into LDS (one-time) ----
    {
        const uint4* src = (const uint4*)wprep + ((size_t)(wsel * 64 + cu8) * 8192);
        uint4* dst = (uint4*)smem;
        #pragma unroll
        for (int i = 0; i < 16; ++i) dst[tid + i * 512] = src[tid + i * 512];
    }
    for (int i = tid; i < 8 * 132; i += 512) cst[i] = 0.f;
    __syncthreads();

    // ---- loop invariants ----
    int lenv[4];
    #pragma unroll
    for (int nt = 0; nt < 4; ++nt) lenv[nt] = lens[(nh * 4 + nt) * 16 + l15];

    const int cu_u = tid >> 5, cu_b = tid & 31;       // cell role (tid < 256)
    float bias_c[4];
    int   len_c[4];
    if (tid < 256) {
        #pragma unroll
        for (int q = 0; q < 4; ++q) bias_c[q] = bsum[wsel * 2048 + q * 512 + hj0 + cu_u];
        #pragma unroll
        for (int c = 0; c < 4; ++c) {
            int gb = (cu_b < 16) ? (c * 16 + cu_b) : (64 + c * 16 + (cu_b - 16));
            len_c[c] = lens[gb];
        }
    }

    const size_t lofs = (size_t)lane * 8;

    for (int tau = 0; tau <= 200; ++tau) {
        const int t = slot ? (tau - 1) : tau;
        const bool active = (t >= 0 && t <= 199);
        int t_eff = 0, p_w = 0, p_r = 0;
        if (active) { t_eff = dir ? (199 - t) : t; p_w = t & 3; p_r = (t + 3) & 3; }

        f32x4 acc[2][4];
        #pragma unroll
        for (int mt = 0; mt < 2; ++mt)
            #pragma unroll
            for (int nt = 0; nt < 4; ++nt)
                acc[mt][nt] = (f32x4){0.f, 0.f, 0.f, 0.f};

        // ---- Phase 1 (slot0 only): ih * x_t (split-bf16) — recurrence-independent ----
        if (slot == 0 && active) {
            const unsigned short* XH = xh + (size_t)t_eff * 65536;
            const unsigned short* XL = xl + (size_t)t_eff * 65536;
            #pragma unroll
            for (int kcl = 0; kcl < 4; ++kcl) {
                int kc = kh * 4 + kcl;
                bf16x8 bxh[4], bxl[4];
                #pragma unroll
                for (int nt = 0; nt < 4; ++nt) {
                    size_t bo = (size_t)(nh * 4 + nt) * 8192 + (size_t)kc * 512 + lofs;
                    bxh[nt] = *(const bf16x8*)(XH + bo);
                    bxl[nt] = *(const bf16x8*)(XL + bo);
                }
                #pragma unroll
                for (int mt = 0; mt < 2; ++mt) {
                    const char* ab = smem + mt * 16384 + kc * 1024 + lane * 16;
                    bf16x8 aih = *(const bf16x8*)(ab);
                    bf16x8 ail = *(const bf16x8*)(ab + 32768);
                    #pragma unroll
                    for (int nt = 0; nt < 4; ++nt) {
                        f32x4 a = acc[mt][nt];
                        a = __builtin_amdgcn_mfma_f32_16x16x32_bf16(aih, bxh[nt], a, 0, 0, 0);
                        a = __builtin_amdgcn_mfma_f32_16x16x32_bf16(aih, bxl[nt], a, 0, 0, 0);
                        a = __builtin_amdgcn_mfma_f32_16x16x32_bf16(ail, bxh[nt], a, 0, 0, 0);
                        acc[mt][nt] = a;
                    }
                }
            }
        }

        // ---- wait for dependencies (parallel wave polls, no RMW contention) ----
        {
            unsigned tgt = (unsigned)tau;
            if (wv == 0) wait_flags(own_f, tgt);                       // own unit done tau-1
            if (slot == 1) { if (wv == 1) wait_flags(sib_f, tgt); }    // data dep
            else if (tau >= 3) { if (wv == 1) wait_flags(sib_f, tgt - 2); }  // WAR (quad-buf)
        }
        __syncthreads();

        if (active) {
            const unsigned short* HH = hbuf + ((size_t)((slot * 4 + p_r) * 2 + dir) << 16);

            // ---- Phase 2: recurrent terms via fp16 h (split-fp16 weights) ----
            if (slot == 0) {
                uint4 vh[4][4];
                #pragma unroll
                for (int kcl = 0; kcl < 4; ++kcl)
                    #pragma unroll
                    for (int nt = 0; nt < 4; ++nt) {
                        size_t bo = (size_t)(nh * 4 + nt) * 8192
                                  + (size_t)(kh * 4 + kcl) * 512 + lofs;
                        ldg_c(vh[kcl][nt], HH + bo);
                    }
                vm_drain();
                #pragma unroll
                for (int kcl = 0; kcl < 4; ++kcl) {
                    int kc = kh * 4 + kcl;
                    #pragma unroll
                    for (int mt = 0; mt < 2; ++mt) {
                        const char* ab = smem + mt * 16384 + kc * 1024 + lane * 16;
                        f16x8 ahh = *(const f16x8*)(ab + 65536);
                        f16x8 ahl = *(const f16x8*)(ab + 98304);
                        #pragma unroll
                        for (int nt = 0; nt < 4; ++nt) {
                            f16x8 bh = __builtin_bit_cast(f16x8, vh[kcl][nt]);
                            f32x4 a = acc[mt][nt];
                            a = __builtin_amdgcn_mfma_f32_16x16x32_f16(ahh, bh, a, 0, 0, 0);
                            a = __builtin_amdgcn_mfma_f32_16x16x32_f16(ahl, bh, a, 0, 0, 0);
                            acc[mt][nt] = a;
                        }
                    }
                }
            } else {
                int p_x = t & 3;                      // layer0 wrote h_t at parity t&3
                const unsigned short* XHc = hbuf + ((size_t)(p_x * 2 + dir) << 16);
                uint4 vx[4][4], vh[4][4];
                #pragma unroll
                for (int kcl = 0; kcl < 4; ++kcl)
                    #pragma unroll
                    for (int nt = 0; nt < 4; ++nt) {
                        size_t bo = (size_t)(nh * 4 + nt) * 8192
                                  + (size_t)(kh * 4 + kcl) * 512 + lofs;
                        ldg_c(vx[kcl][nt], XHc + bo);
                        ldg_c(vh[kcl][nt], HH + bo);
                    }
                vm_drain();
                #pragma unroll
                for (int kcl = 0; kcl < 4; ++kcl) {
                    int kc = kh * 4 + kcl;
                    #pragma unroll
                    for (int nt = 0; nt < 4; ++nt)
                        if (!(t_eff < lenv[nt]))
                            vx[kcl][nt] = make_uint4(0, 0, 0, 0);
                    #pragma unroll
                    for (int mt = 0; mt < 2; ++mt) {
                        const char* ab = smem + mt * 16384 + kc * 1024 + lane * 16;
                        f16x8 aih = *(const f16x8*)(ab);
                        f16x8 ail = *(const f16x8*)(ab + 32768);
                        f16x8 ahh = *(const f16x8*)(ab + 65536);
                        f16x8 ahl = *(const f16x8*)(ab + 98304);
                        #pragma unroll
                        for (int nt = 0; nt < 4; ++nt) {
                            f16x8 xv = __builtin_bit_cast(f16x8, vx[kcl][nt]);
                            f16x8 bh = __builtin_bit_cast(f16x8, vh[kcl][nt]);
                            f32x4 a = acc[mt][nt];
                            a = __builtin_amdgcn_mfma_f32_16x16x32_f16(aih, xv, a, 0, 0, 0);
                            a = __builtin_amdgcn_mfma_f32_16x16x32_f16(ail, xv, a, 0, 0, 0);
                            a = __builtin_amdgcn_mfma_f32_16x16x32_f16(ahh, bh, a, 0, 0, 0);
                            a = __builtin_amdgcn_mfma_f32_16x16x32_f16(ahl, bh, a, 0, 0, 0);
                            acc[mt][nt] = a;
                        }
                    }
                }
            }

            unsigned short* Hw = hbuf + ((size_t)((slot * 4 + p_w) * 2 + dir) << 16);

            const int crow = (lane >> 4) * 4;
            #pragma unroll
            for (int c = 0; c < 4; ++c) {
                #pragma unroll
                for (int mt = 0; mt < 2; ++mt)
                    #pragma unroll
                    for (int r = 0; r < 4; ++r) {
                        int rr = mt * 16 + crow + r;
                        exch[(kh * 32 + rr) * 33 + nh * 16 + l15] = acc[mt][c][r];
                    }
                __syncthreads();
                if (tid < 256) {
                    float g[4];
                    #pragma unroll
                    for (int q = 0; q < 4; ++q) {
                        int row = q * 8 + cu_u;
                        g[q] = exch[(0 + row) * 33 + cu_b] + exch[(32 + row) * 33 + cu_b]
                             + exch[(64 + row) * 33 + cu_b] + exch[(96 + row) * 33 + cu_b]
                             + bias_c[q];
                    }
                    int gb = (cu_b < 16) ? (c * 16 + cu_b) : (64 + c * 16 + (cu_b - 16));
                    float cv = cst[cu_u * 132 + gb];
                    float iG = 1.f / (1.f + expf(-g[0]));
                    float fG = 1.f / (1.f + expf(-g[1]));
                    float gG = tanhf(g[2]);
                    float oG = 1.f / (1.f + expf(-g[3]));
                    float cn = fG * cv + iG * gG;
                    cst[cu_u * 132 + gb] = cn;
                    float hn = oG * tanhf(cn);
                    _Float16 hf = (_Float16)hn;
                    int hj = hj0 + cu_u;
                    size_t ho = (((size_t)(gb >> 4) * 16 + (hj >> 5)) * 64
                                 + ((hj >> 3) & 3) * 16 + (gb & 15)) * 8 + (hj & 7);
                    stg_c16(Hw + ho, __builtin_bit_cast(unsigned short, hf));
                    if (slot) {
                        float hm = (t_eff < len_c[c]) ? hn : 0.f;
                        dout[((size_t)gb * 200 + t_eff) * 1024 + dir * 512 + hj] = hm;
                    }
                }
                __syncthreads();
            }
            // drain the coherent h stores (asm stores are invisible to the
            // compiler's barrier waitcnt) before signaling completion
            if (tid < 256) asm volatile("s_waitcnt vmcnt(0)" ::: "memory");
            __syncthreads();
        }

        // ---- signal completion of iteration tau (plain coherent store, no RMW) ----
        if (tid == 0)
            __hip_atomic_store(own_f + cu8, (unsigned)(tau + 1),
                               __ATOMIC_RELAXED, __HIP_MEMORY_SCOPE_AGENT);
    }
}

// ---------------- host ----------------
extern "C" void kernel_launch(void* const* d_in, const int* in_sizes, int n_in,
                              void* d_out, int out_size, void* d_ws, size_t ws_size,
                              hipStream_t stream) {
    const float* x     = (const float*)d_in[0];
    const int*   lens  = (const int*)d_in[1];     // int32 (JAX x64-disabled)
    const float* Wih_f = (const float*)d_in[2];
    const float* Whh_f = (const float*)d_in[3];
    const float* bih_f = (const float*)d_in[4];
    const float* bhh_f = (const float*)d_in[5];
    const float* Wih_b = (const float*)d_in[6];
    const float* Whh_b = (const float*)d_in[7];
    const float* bih_b = (const float*)d_in[8];
    const float* bhh_b = (const float*)d_in[9];
    float* out = (float*)d_out;
    char* ws = (char*)d_ws;
    if (ws_size < 88114176) return;

    unsigned short* xh    = (unsigned short*)(ws);                 // 26,214,400
    unsigned short* xl    = (unsigned short*)(ws + 26214400);      // 26,214,400
    unsigned short* wprep = (unsigned short*)(ws + 52428800);      // 33,554,432
    float*          bsum  = (float*)(ws + 85983232);               //     32,768
    unsigned short* hbuf  = (unsigned short*)(ws + 86016000);      //  2,097,152 (16 x 128KB)
    unsigned*       flg   = (unsigned*)(ws + 88113152);            //      1,024

    prep_x<<<6400, 256, 0, stream>>>(x, xh, xl);
    prep_w<<<1024, 256, 0, stream>>>(Wih_f, wprep, 0, 0);
    prep_w<<<1024, 256, 0, stream>>>(Whh_f, wprep, 0, 1);
    prep_w<<<1024, 256, 0, stream>>>(Wih_b, wprep, 1, 0);
    prep_w<<<1024, 256, 0, stream>>>(Whh_b, wprep, 1, 1);
    bsum_k<<<32, 256, 0, stream>>>(bih_f, bhh_f, bih_b, bhh_b, bsum);
    reset_k<<<513, 256, 0, stream>>>((uint4*)hbuf);   // zeroes hbuf | flags (contiguous)

    static const int LDS_BYTES = 131072 + 16896 + 4224;  // 152,192
    hipFuncSetAttribute(reinterpret_cast<const void*>(lstm_persist),
                        hipFuncAttributeMaxDynamicSharedMemorySize, LDS_BYTES);

    void* args[] = {(void*)&xh, (void*)&xl, (void*)&wprep, (void*)&bsum,
                    (void*)&hbuf, (void*)&lens, (void*)&out, (void*)&flg};
    hipLaunchCooperativeKernel(reinterpret_cast<void*>(lstm_persist),
                               dim3(256), dim3(512), args, LDS_BYTES, stream);
}

// Round 10
// 1771.506 us; speedup vs baseline: 1.8403x; 1.3897x over previous
//
#include <hip/hip_runtime.h>
#include <hip/hip_bf16.h>

typedef __bf16 bf16x8 __attribute__((ext_vector_type(8)));
typedef _Float16 f16x8 __attribute__((ext_vector_type(8)));
typedef float f32x4 __attribute__((ext_vector_type(4)));

__device__ __forceinline__ unsigned short f2bf(float f) {
    unsigned int u = __builtin_bit_cast(unsigned int, f);
    u += 0x7FFFu + ((u >> 16) & 1u);
    return (unsigned short)(u >> 16);
}
__device__ __forceinline__ float bf2f(unsigned short s) {
    unsigned int u = ((unsigned int)s) << 16;
    return __builtin_bit_cast(float, u);
}

// Coherent (L1/L2-bypass, L3-served) 16B load: issue only; caller batches one
// s_waitcnt vmcnt(0) + sched_barrier afterwards (guide §5.5 rule 18).
__device__ __forceinline__ void ldg_c(uint4& d, const void* p) {
    asm volatile("global_load_dwordx4 %0, %1, off sc0 sc1" : "=v"(d) : "v"(p));
}
__device__ __forceinline__ void vm_drain() {
    asm volatile("s_waitcnt vmcnt(0)" ::: "memory");
    __builtin_amdgcn_sched_barrier(0);
}
__device__ __forceinline__ void lds_fence() {
    asm volatile("s_waitcnt lgkmcnt(0)" ::: "memory");
    __builtin_amdgcn_sched_barrier(0);
}
// Coherent write-through 16-bit store.
__device__ __forceinline__ void stg_c16(void* p, unsigned short v) {
    asm volatile("global_store_short %0, %1, off sc0 sc1" :: "v"(p), "v"(v) : "memory");
}

// Wave-parallel flag wait: 64 lanes each watch one CU's flag word.
__device__ __forceinline__ void wait_flags(const unsigned* f, unsigned tgt) {
    int lane = threadIdx.x & 63;
    for (;;) {
        unsigned v = __hip_atomic_load(f + lane, __ATOMIC_RELAXED, __HIP_MEMORY_SCOPE_AGENT);
        if (__all((int)(v >= tgt))) break;
        __builtin_amdgcn_s_sleep(1);
    }
}

// ---------------- prep: x -> split bf16 hi/lo in MFMA B-fragment layout ----------------
// layout: [t(200)][nt(8)][kc(16)][lane(64)][e(8)]; batch = nt*16+(lane&15), k = kc*32+(lane>>4)*8+e
__global__ void prep_x(const float* __restrict__ x,
                       unsigned short* __restrict__ xh,
                       unsigned short* __restrict__ xl) {
    int g = blockIdx.x * 256 + threadIdx.x;   // 1,638,400 frags
    if (g >= 1638400) return;
    int lane = g & 63;
    int kc   = (g >> 6) & 15;
    int nt   = (g >> 10) & 7;
    int t    = g >> 13;
    int batch = nt * 16 + (lane & 15);
    int k = kc * 32 + (lane >> 4) * 8;
    const float* s = x + ((size_t)batch * 200 + t) * 512 + k;
    float4 v0 = *(const float4*)s;
    float4 v1 = *(const float4*)(s + 4);
    float vv[8] = {v0.x, v0.y, v0.z, v0.w, v1.x, v1.y, v1.z, v1.w};
    unsigned int ph[4], pl[4];
    #pragma unroll
    for (int j = 0; j < 4; ++j) {
        float a = vv[2*j], b = vv[2*j+1];
        unsigned short ha = f2bf(a), hb = f2bf(b);
        unsigned short la = f2bf(a - bf2f(ha)), lb = f2bf(b - bf2f(hb));
        ph[j] = (unsigned)ha | ((unsigned)hb << 16);
        pl[j] = (unsigned)la | ((unsigned)lb << 16);
    }
    ((uint4*)xh)[g] = make_uint4(ph[0], ph[1], ph[2], ph[3]);
    ((uint4*)xl)[g] = make_uint4(pl[0], pl[1], pl[2], pl[3]);
}

// ---------------- prep: weights -> per-CU LDS image blocks ----------------
// dst block per (wu = dir*2+layer, cu 0..63): 8192 frags of 16B (131072 B):
//   frag idx within block = mat*2048 + mt*1024 + kc*64 + lane
//   mat: 0=ihH 1=ihL 2=hhH 3=hhL
// Format: layer0 ih = split-bf16 (multiplies x); layer1 ih and all hh =
// split-fp16 (multiply fp16 h streams).
__global__ void prep_w(const float* __restrict__ W,     // [2][2048][512] f32
                       unsigned short* __restrict__ wprep,
                       int dir, int isHH) {
    int g = blockIdx.x * 256 + threadIdx.x;   // 262,144
    if (g >= 262144) return;
    int lane = g & 63;
    int kc   = (g >> 6) & 15;
    int mt   = (g >> 10) & 1;
    int cu   = (g >> 11) & 63;
    int l    = g >> 17;
    int r = lane & 15;
    int grow = (2 * mt + (r >> 3)) * 512 + cu * 8 + (r & 7);
    int k = kc * 32 + (lane >> 4) * 8;
    const float* s = W + ((size_t)l * 2048 + grow) * 512 + k;
    float4 v0 = *(const float4*)s;
    float4 v1 = *(const float4*)(s + 4);
    float vv[8] = {v0.x, v0.y, v0.z, v0.w, v1.x, v1.y, v1.z, v1.w};
    bool f16fmt = isHH || (l == 1);
    unsigned int ph[4], pl[4];
    #pragma unroll
    for (int j = 0; j < 4; ++j) {
        float a = vv[2*j], b = vv[2*j+1];
        unsigned short ha, hb, la, lb;
        if (f16fmt) {
            _Float16 fa = (_Float16)a, fb = (_Float16)b;
            _Float16 ra = (_Float16)(a - (float)fa), rb = (_Float16)(b - (float)fb);
            ha = __builtin_bit_cast(unsigned short, fa);
            hb = __builtin_bit_cast(unsigned short, fb);
            la = __builtin_bit_cast(unsigned short, ra);
            lb = __builtin_bit_cast(unsigned short, rb);
        } else {
            ha = f2bf(a); hb = f2bf(b);
            la = f2bf(a - bf2f(ha)); lb = f2bf(b - bf2f(hb));
        }
        ph[j] = (unsigned)ha | ((unsigned)hb << 16);
        pl[j] = (unsigned)la | ((unsigned)lb << 16);
    }
    size_t blk = ((size_t)(dir * 2 + l) * 64 + cu) * 8192;
    size_t fH = blk + (size_t)((isHH * 2 + 0) * 2048 + mt * 1024 + kc * 64 + lane);
    size_t fL = blk + (size_t)((isHH * 2 + 1) * 2048 + mt * 1024 + kc * 64 + lane);
    ((uint4*)wprep)[fH] = make_uint4(ph[0], ph[1], ph[2], ph[3]);
    ((uint4*)wprep)[fL] = make_uint4(pl[0], pl[1], pl[2], pl[3]);
}

__global__ void bsum_k(const float* __restrict__ bih_f, const float* __restrict__ bhh_f,
                       const float* __restrict__ bih_b, const float* __restrict__ bhh_b,
                       float* __restrict__ bsum) {
    int i = blockIdx.x * 256 + threadIdx.x;   // 8192 = [dir][l][2048]
    if (i < 8192) {
        int dir = i >> 12, rem = i & 4095;
        const float* bi = dir ? bih_b : bih_f;
        const float* bh = dir ? bhh_b : bhh_f;
        bsum[i] = bi[rem] + bh[rem];
    }
}

__global__ void reset_k(uint4* __restrict__ p) {  // zero hbuf | flags (2,098,176 B)
    int g = blockIdx.x * 256 + threadIdx.x;
    if (g < 131136) p[g] = make_uint4(0, 0, 0, 0);
}

// ---------------- persistent LSTM (cooperative launch, flag-vector barriers) --------
// 256 WGs (1/CU) x 512 threads. unit = xcd>>1 (slot=unit>>1, dir=unit&1);
// CU owns 8 hidden units (hj0 = cu8*8): gate rows {q*512+hj0..+7}, all 128 batches.
// N-MAJOR wave split: wave ng (0..7) owns batches ng*16..+15 and ALL of K ->
// complete gates in registers, no cross-wave reduction, no per-step syncthreads
// except one before the signal. Per-wave 2KB LDS transpose for the cell update.
// Weights LDS-resident; c-state in LDS; h = fp16 quad-buffered in global via
// sc0/sc1-coherent accesses; per-CU flag-word barrier.
__global__ void __launch_bounds__(512)
lstm_persist(const unsigned short* __restrict__ xh,
             const unsigned short* __restrict__ xl,
             const unsigned short* __restrict__ wprep,
             const float*          __restrict__ bsum,
             unsigned short*       __restrict__ hbuf,   // [(slot*4+parity)*2+dir] x 65536 fp16
             const int*            __restrict__ lens,
             float*                __restrict__ dout,   // [128][200][1024]
             unsigned*             __restrict__ flagv)  // [unit4][cu64]
{
    extern __shared__ char smem[];
    float* wexch = (float*)(smem + 131072);           // [ng8][32][17] = 17,408 B
    float* cst   = (float*)(smem + 131072 + 17408);   // [u8][132]    =  4,224 B

    const int bid  = blockIdx.x;
    const int xcd  = bid & 7;
    const int unit = xcd >> 1;                        // slot-major: slot*2 + dir
    const int slot = unit >> 1, dir = unit & 1;
    const int cu8  = ((xcd & 1) << 5) | (bid >> 3);   // 0..63
    const int hj0  = cu8 * 8;
    const int tid  = threadIdx.x;
    const int lane = tid & 63, ng = tid >> 6;         // wave = batch group
    const int l15  = lane & 15, kg = lane >> 4;
    const int wsel = dir * 2 + slot;                  // dir-major, matches prep_w/bsum

    const int sib = slot ? dir : (2 + dir);           // other slot, same dir
    unsigned* own_f = flagv + unit * 64;
    unsigned* sib_f = flagv + sib * 64;

    // ---- stage weights into LDS (one-time) ----
    {
        const uint4* src = (const uint4*)wprep + ((size_t)(wsel * 64 + cu8) * 8192);
        uint4* dst = (uint4*)smem;
        #pragma unroll
        for (int i = 0; i < 16; ++i) dst[tid + i * 512] = src[tid + i * 512];
    }
    for (int i = tid; i < 8 * 132; i += 512) cst[i] = 0.f;
    __syncthreads();

    // ---- loop invariants ----
    const int lenv = lens[ng * 16 + l15];             // mask batch for B-frags (slot1)
    const int u    = lane >> 3;                       // cell hidden unit 0..7
    const int b2   = 2 * (lane & 7);                  // cell batch pair within group
    const int gbA  = ng * 16 + b2, gbB = gbA + 1;
    const int lenA = lens[gbA], lenB = lens[gbB];
    const int hj   = hj0 + u;
    float bias_c[4];
    #pragma unroll
    for (int q = 0; q < 4; ++q) bias_c[q] = bsum[wsel * 2048 + q * 512 + hj];
    float* wex = wexch + ng * 32 * 17;
    const size_t lofs = (size_t)lane * 8;

    for (int tau = 0; tau <= 200; ++tau) {
        const int t = slot ? (tau - 1) : tau;
        const bool active = (t >= 0 && t <= 199);
        int t_eff = 0, p_w = 0, p_r = 0;
        if (active) { t_eff = dir ? (199 - t) : t; p_w = t & 3; p_r = (t + 3) & 3; }

        f32x4 acc0 = {0.f, 0.f, 0.f, 0.f};
        f32x4 acc1 = {0.f, 0.f, 0.f, 0.f};

        // ---- Phase 1 (slot0 only): ih * x_t (split-bf16) — recurrence-independent ----
        if (slot == 0 && active) {
            const unsigned short* XH = xh + (size_t)t_eff * 65536;
            const unsigned short* XL = xl + (size_t)t_eff * 65536;
            #pragma unroll
            for (int kc = 0; kc < 16; ++kc) {
                size_t bo = (size_t)ng * 8192 + (size_t)kc * 512 + lofs;
                bf16x8 bxh = *(const bf16x8*)(XH + bo);
                bf16x8 bxl = *(const bf16x8*)(XL + bo);
                const char* ab = smem + kc * 1024 + lane * 16;
                bf16x8 aih0 = *(const bf16x8*)(ab);
                bf16x8 ail0 = *(const bf16x8*)(ab + 32768);
                bf16x8 aih1 = *(const bf16x8*)(ab + 16384);
                bf16x8 ail1 = *(const bf16x8*)(ab + 16384 + 32768);
                acc0 = __builtin_amdgcn_mfma_f32_16x16x32_bf16(aih0, bxh, acc0, 0, 0, 0);
                acc0 = __builtin_amdgcn_mfma_f32_16x16x32_bf16(aih0, bxl, acc0, 0, 0, 0);
                acc0 = __builtin_amdgcn_mfma_f32_16x16x32_bf16(ail0, bxh, acc0, 0, 0, 0);
                acc1 = __builtin_amdgcn_mfma_f32_16x16x32_bf16(aih1, bxh, acc1, 0, 0, 0);
                acc1 = __builtin_amdgcn_mfma_f32_16x16x32_bf16(aih1, bxl, acc1, 0, 0, 0);
                acc1 = __builtin_amdgcn_mfma_f32_16x16x32_bf16(ail1, bxh, acc1, 0, 0, 0);
            }
        }

        // ---- wait for dependencies (parallel wave polls, no RMW contention) ----
        {
            unsigned tgt = (unsigned)tau;
            if (ng == 0) wait_flags(own_f, tgt);                       // own unit done tau-1
            if (slot == 1) { if (ng == 1) wait_flags(sib_f, tgt); }    // data dep
            else if (tau >= 3) { if (ng == 1) wait_flags(sib_f, tgt - 2); }  // WAR (quad-buf)
        }
        __syncthreads();

        if (active) {
            const unsigned short* HH = hbuf + ((size_t)((slot * 4 + p_r) * 2 + dir) << 16);

            // ---- Phase 2: recurrent terms via fp16 h (split-fp16 weights) ----
            if (slot == 0) {
                uint4 vh[16];
                #pragma unroll
                for (int kc = 0; kc < 16; ++kc)
                    ldg_c(vh[kc], HH + (size_t)ng * 8192 + (size_t)kc * 512 + lofs);
                vm_drain();
                #pragma unroll
                for (int kc = 0; kc < 16; ++kc) {
                    f16x8 bh = __builtin_bit_cast(f16x8, vh[kc]);
                    const char* ab = smem + kc * 1024 + lane * 16;
                    f16x8 ahh0 = *(const f16x8*)(ab + 65536);
                    f16x8 ahl0 = *(const f16x8*)(ab + 98304);
                    f16x8 ahh1 = *(const f16x8*)(ab + 16384 + 65536);
                    f16x8 ahl1 = *(const f16x8*)(ab + 16384 + 98304);
                    acc0 = __builtin_amdgcn_mfma_f32_16x16x32_f16(ahh0, bh, acc0, 0, 0, 0);
                    acc0 = __builtin_amdgcn_mfma_f32_16x16x32_f16(ahl0, bh, acc0, 0, 0, 0);
                    acc1 = __builtin_amdgcn_mfma_f32_16x16x32_f16(ahh1, bh, acc1, 0, 0, 0);
                    acc1 = __builtin_amdgcn_mfma_f32_16x16x32_f16(ahl1, bh, acc1, 0, 0, 0);
                }
            } else {
                int p_x = t & 3;                      // layer0 wrote h_t at parity t&3
                const unsigned short* XHc = hbuf + ((size_t)(p_x * 2 + dir) << 16);
                uint4 vx[16], vh[16];
                #pragma unroll
                for (int kc = 0; kc < 16; ++kc) {
                    size_t bo = (size_t)ng * 8192 + (size_t)kc * 512 + lofs;
                    ldg_c(vx[kc], XHc + bo);
                    ldg_c(vh[kc], HH + bo);
                }
                vm_drain();
                const bool mv = (t_eff < lenv);
                #pragma unroll
                for (int kc = 0; kc < 16; ++kc) {
                    if (!mv) vx[kc] = make_uint4(0, 0, 0, 0);
                    f16x8 xv = __builtin_bit_cast(f16x8, vx[kc]);
                    f16x8 bh = __builtin_bit_cast(f16x8, vh[kc]);
                    const char* ab = smem + kc * 1024 + lane * 16;
                    f16x8 aih0 = *(const f16x8*)(ab);
                    f16x8 ail0 = *(const f16x8*)(ab + 32768);
                    f16x8 ahh0 = *(const f16x8*)(ab + 65536);
                    f16x8 ahl0 = *(const f16x8*)(ab + 98304);
                    f16x8 aih1 = *(const f16x8*)(ab + 16384);
                    f16x8 ail1 = *(const f16x8*)(ab + 16384 + 32768);
                    f16x8 ahh1 = *(const f16x8*)(ab + 16384 + 65536);
                    f16x8 ahl1 = *(const f16x8*)(ab + 16384 + 98304);
                    acc0 = __builtin_amdgcn_mfma_f32_16x16x32_f16(aih0, xv, acc0, 0, 0, 0);
                    acc0 = __builtin_amdgcn_mfma_f32_16x16x32_f16(ail0, xv, acc0, 0, 0, 0);
                    acc0 = __builtin_amdgcn_mfma_f32_16x16x32_f16(ahh0, bh, acc0, 0, 0, 0);
                    acc0 = __builtin_amdgcn_mfma_f32_16x16x32_f16(ahl0, bh, acc0, 0, 0, 0);
                    acc1 = __builtin_amdgcn_mfma_f32_16x16x32_f16(aih1, xv, acc1, 0, 0, 0);
                    acc1 = __builtin_amdgcn_mfma_f32_16x16x32_f16(ail1, xv, acc1, 0, 0, 0);
                    acc1 = __builtin_amdgcn_mfma_f32_16x16x32_f16(ahh1, bh, acc1, 0, 0, 0);
                    acc1 = __builtin_amdgcn_mfma_f32_16x16x32_f16(ahl1, bh, acc1, 0, 0, 0);
                }
            }

            // ---- per-wave cell update: acc -> LDS transpose -> 2 cells/lane ----
            #pragma unroll
            for (int r = 0; r < 4; ++r) {
                wex[(kg * 4 + r) * 17 + l15]        = acc0[r];
                wex[(16 + kg * 4 + r) * 17 + l15]   = acc1[r];
            }
            lds_fence();   // intra-wave write->read ordering; no cross-wave deps

            unsigned short* Hw = hbuf + ((size_t)((slot * 4 + p_w) * 2 + dir) << 16);
            #pragma unroll
            for (int j = 0; j < 2; ++j) {
                int b  = b2 + j;
                int gb = ng * 16 + b;
                float g0 = wex[(0 * 8 + u) * 17 + b] + bias_c[0];
                float g1 = wex[(1 * 8 + u) * 17 + b] + bias_c[1];
                float g2 = wex[(2 * 8 + u) * 17 + b] + bias_c[2];
                float g3 = wex[(3 * 8 + u) * 17 + b] + bias_c[3];
                float cv = cst[u * 132 + gb];
                float iG = 1.f / (1.f + expf(-g0));
                float fG = 1.f / (1.f + expf(-g1));
                float gG = tanhf(g2);
                float oG = 1.f / (1.f + expf(-g3));
                float cn = fG * cv + iG * gG;
                cst[u * 132 + gb] = cn;
                float hn = oG * tanhf(cn);
                _Float16 hf = (_Float16)hn;
                size_t ho = (((size_t)ng * 16 + (hj >> 5)) * 64
                             + ((hj >> 3) & 3) * 16 + b) * 8 + (hj & 7);
                stg_c16(Hw + ho, __builtin_bit_cast(unsigned short, hf));
                if (slot) {
                    float hm = (t_eff < (j ? lenB : lenA)) ? hn : 0.f;
                    dout[((size_t)gb * 200 + t_eff) * 1024 + dir * 512 + hj] = hm;
                }
            }
            vm_drain();    // every lane drains its own coherent h stores
        }

        __syncthreads();   // all waves' h stores drained before the signal
        if (tid == 0)
            __hip_atomic_store(own_f + cu8, (unsigned)(tau + 1),
                               __ATOMIC_RELAXED, __HIP_MEMORY_SCOPE_AGENT);
    }
}

// ---------------- host ----------------
extern "C" void kernel_launch(void* const* d_in, const int* in_sizes, int n_in,
                              void* d_out, int out_size, void* d_ws, size_t ws_size,
                              hipStream_t stream) {
    const float* x     = (const float*)d_in[0];
    const int*   lens  = (const int*)d_in[1];     // int32 (JAX x64-disabled)
    const float* Wih_f = (const float*)d_in[2];
    const float* Whh_f = (const float*)d_in[3];
    const float* bih_f = (const float*)d_in[4];
    const float* bhh_f = (const float*)d_in[5];
    const float* Wih_b = (const float*)d_in[6];
    const float* Whh_b = (const float*)d_in[7];
    const float* bih_b = (const float*)d_in[8];
    const float* bhh_b = (const float*)d_in[9];
    float* out = (float*)d_out;
    char* ws = (char*)d_ws;
    if (ws_size < 88114176) return;

    unsigned short* xh    = (unsigned short*)(ws);                 // 26,214,400
    unsigned short* xl    = (unsigned short*)(ws + 26214400);      // 26,214,400
    unsigned short* wprep = (unsigned short*)(ws + 52428800);      // 33,554,432
    float*          bsum  = (float*)(ws + 85983232);               //     32,768
    unsigned short* hbuf  = (unsigned short*)(ws + 86016000);      //  2,097,152 (16 x 128KB)
    unsigned*       flg   = (unsigned*)(ws + 88113152);            //      1,024

    prep_x<<<6400, 256, 0, stream>>>(x, xh, xl);
    prep_w<<<1024, 256, 0, stream>>>(Wih_f, wprep, 0, 0);
    prep_w<<<1024, 256, 0, stream>>>(Whh_f, wprep, 0, 1);
    prep_w<<<1024, 256, 0, stream>>>(Wih_b, wprep, 1, 0);
    prep_w<<<1024, 256, 0, stream>>>(Whh_b, wprep, 1, 1);
    bsum_k<<<32, 256, 0, stream>>>(bih_f, bhh_f, bih_b, bhh_b, bsum);
    reset_k<<<513, 256, 0, stream>>>((uint4*)hbuf);   // zeroes hbuf | flags (contiguous)

    static const int LDS_BYTES = 131072 + 17408 + 4224;  // 152,704
    hipFuncSetAttribute(reinterpret_cast<const void*>(lstm_persist),
                        hipFuncAttributeMaxDynamicSharedMemorySize, LDS_BYTES);

    void* args[] = {(void*)&xh, (void*)&xl, (void*)&wprep, (void*)&bsum,
                    (void*)&hbuf, (void*)&lens, (void*)&out, (void*)&flg};
    hipLaunchCooperativeKernel(reinterpret_cast<void*>(lstm_persist),
                               dim3(256), dim3(512), args, LDS_BYTES, stream);
}